// Round 1
// baseline (125.948 us; speedup 1.0000x reference)
//
#include <hip/hip_runtime.h>

// DCN cross network, collapsed form:
//   x_{i+1} = x0 * dot(x_i, w_i) + b_i + x_i
// B=16384, D=1024, L=4. One wave (64 lanes) per row; 16 floats/lane in
// registers; wave-shuffle butterfly for the per-row dot. Memory-bound:
// 64 MiB in + 64 MiB out.

#define D 1024
#define LAYERS 4
#define CHUNKS 4   // 1024 floats / (64 lanes * 4 floats per float4)

__global__ __launch_bounds__(256) void cross_network_kernel(
    const float* __restrict__ x,
    const float* __restrict__ w,   // [LAYERS, D]
    const float* __restrict__ b,   // [LAYERS, D]
    float* __restrict__ out,
    int batch)
{
    const int wave = (int)((blockIdx.x * blockDim.x + threadIdx.x) >> 6);
    const int lane = (int)(threadIdx.x & 63);
    if (wave >= batch) return;

    const float4* row = (const float4*)(x + (size_t)wave * D);

    float4 x0[CHUNKS], xi[CHUNKS];
#pragma unroll
    for (int c = 0; c < CHUNKS; ++c) {
        x0[c] = row[c * 64 + lane];
        xi[c] = x0[c];
    }

#pragma unroll
    for (int l = 0; l < LAYERS; ++l) {
        const float4* wl = (const float4*)(w + l * D);
        const float4* bl = (const float4*)(b + l * D);

        // partial dot over this lane's 16 elements
        float s = 0.f;
#pragma unroll
        for (int c = 0; c < CHUNKS; ++c) {
            float4 wv = wl[c * 64 + lane];
            s = fmaf(xi[c].x, wv.x, s);
            s = fmaf(xi[c].y, wv.y, s);
            s = fmaf(xi[c].z, wv.z, s);
            s = fmaf(xi[c].w, wv.w, s);
        }
        // 64-lane butterfly reduction (wave = 64 on CDNA)
#pragma unroll
        for (int off = 32; off > 0; off >>= 1)
            s += __shfl_xor(s, off, 64);

        // x_{i+1} = x0 * s + b + x_i
#pragma unroll
        for (int c = 0; c < CHUNKS; ++c) {
            float4 bv = bl[c * 64 + lane];
            xi[c].x = fmaf(x0[c].x, s, bv.x + xi[c].x);
            xi[c].y = fmaf(x0[c].y, s, bv.y + xi[c].y);
            xi[c].z = fmaf(x0[c].z, s, bv.z + xi[c].z);
            xi[c].w = fmaf(x0[c].w, s, bv.w + xi[c].w);
        }
    }

    float4* orow = (float4*)(out + (size_t)wave * D);
#pragma unroll
    for (int c = 0; c < CHUNKS; ++c)
        orow[c * 64 + lane] = xi[c];
}

extern "C" void kernel_launch(void* const* d_in, const int* in_sizes, int n_in,
                              void* d_out, int out_size, void* d_ws, size_t ws_size,
                              hipStream_t stream) {
    const float* x = (const float*)d_in[0];
    const float* w = (const float*)d_in[1];
    const float* b = (const float*)d_in[2];
    float* out = (float*)d_out;

    const int batch = in_sizes[0] / D;      // 16384
    const int waves_per_block = 256 / 64;   // 4 rows per block
    const int grid = (batch + waves_per_block - 1) / waves_per_block;

    cross_network_kernel<<<grid, 256, 0, stream>>>(x, w, b, out, batch);
}

// Round 2
// 124.288 us; speedup vs baseline: 1.0134x; 1.0134x over previous
//
#include <hip/hip_runtime.h>

// DCN cross network, algebraically collapsed:
//   x_i = c_i * x0 + B_i,  B_i = sum_{j<i} b_j   (row-independent)
//   c_0 = 1,  c_{i+1} = c_i + s_i,  s_i = c_i * d_i + g_i
//   d_i = dot(x0, w_i)   (4 independent dots per row)
//   g_i = dot(B_i, w_i)  (row-independent scalars, precomputed)
// Output: x_4 = c_4 * x0 + Bsum.
// Removes the layer-serial dependency chain entirely: 4 parallel dot
// chains, one 4-way-ILP butterfly, scalar recurrence, one fused store.

#define D 1024
#define LAYERS 4
#define CHUNKS 4

__device__ inline float dot4(float4 a, float4 b) {
    return fmaf(a.x, b.x, fmaf(a.y, b.y, fmaf(a.z, b.z, a.w * b.w)));
}

// ws layout (floats): [0..1023] = Bsum, [1024..1027] = g0..g3 (g0 = 0)
__global__ __launch_bounds__(256) void precompute_kernel(
    const float* __restrict__ w,
    const float* __restrict__ b,
    float* __restrict__ ws)
{
    const int t = threadIdx.x;               // 0..255, each owns 4 floats
    const float4* b4 = (const float4*)b;     // 256 float4 per row
    const float4* w4 = (const float4*)w;

    float4 b0 = b4[t], b1 = b4[256 + t], b2 = b4[512 + t], b3 = b4[768 + t];
    float4 w1 = w4[256 + t], w2 = w4[512 + t], w3 = w4[768 + t];

    float4 s01, s012, bs;
    s01.x = b0.x + b1.x;  s01.y = b0.y + b1.y;
    s01.z = b0.z + b1.z;  s01.w = b0.w + b1.w;
    s012.x = s01.x + b2.x; s012.y = s01.y + b2.y;
    s012.z = s01.z + b2.z; s012.w = s01.w + b2.w;
    bs.x = s012.x + b3.x; bs.y = s012.y + b3.y;
    bs.z = s012.z + b3.z; bs.w = s012.w + b3.w;
    ((float4*)ws)[t] = bs;

    float g1 = dot4(b0, w1);
    float g2 = dot4(s01, w2);
    float g3 = dot4(s012, w3);

#pragma unroll
    for (int off = 32; off > 0; off >>= 1) {
        g1 += __shfl_xor(g1, off, 64);
        g2 += __shfl_xor(g2, off, 64);
        g3 += __shfl_xor(g3, off, 64);
    }

    __shared__ float red[3][4];
    const int wid = t >> 6, lane = t & 63;
    if (lane == 0) { red[0][wid] = g1; red[1][wid] = g2; red[2][wid] = g3; }
    __syncthreads();
    if (t == 0) {
        ws[D + 0] = 0.f;
        ws[D + 1] = red[0][0] + red[0][1] + red[0][2] + red[0][3];
        ws[D + 2] = red[1][0] + red[1][1] + red[1][2] + red[1][3];
        ws[D + 3] = red[2][0] + red[2][1] + red[2][2] + red[2][3];
    }
}

__global__ __launch_bounds__(256) void cross_main_kernel(
    const float* __restrict__ x,
    const float* __restrict__ w,
    const float* __restrict__ ws,
    float* __restrict__ out,
    int batch)
{
    const int wave = (int)((blockIdx.x * blockDim.x + threadIdx.x) >> 6);
    const int lane = (int)(threadIdx.x & 63);
    if (wave >= batch) return;

    const float4* row = (const float4*)(x + (size_t)wave * D);
    const float4* w4  = (const float4*)w;
    const float4* bs4 = (const float4*)ws;

    float4 x0[CHUNKS];
#pragma unroll
    for (int c = 0; c < CHUNKS; ++c) x0[c] = row[c * 64 + lane];

    float d0 = 0.f, d1 = 0.f, d2 = 0.f, d3 = 0.f;
#pragma unroll
    for (int c = 0; c < CHUNKS; ++c) {
        const int idx = c * 64 + lane;
        float4 wv0 = w4[idx];
        float4 wv1 = w4[256 + idx];
        float4 wv2 = w4[512 + idx];
        float4 wv3 = w4[768 + idx];
        // 4 independent FMA chains — full ILP
        d0 = fmaf(x0[c].x, wv0.x, d0); d1 = fmaf(x0[c].x, wv1.x, d1);
        d2 = fmaf(x0[c].x, wv2.x, d2); d3 = fmaf(x0[c].x, wv3.x, d3);
        d0 = fmaf(x0[c].y, wv0.y, d0); d1 = fmaf(x0[c].y, wv1.y, d1);
        d2 = fmaf(x0[c].y, wv2.y, d2); d3 = fmaf(x0[c].y, wv3.y, d3);
        d0 = fmaf(x0[c].z, wv0.z, d0); d1 = fmaf(x0[c].z, wv1.z, d1);
        d2 = fmaf(x0[c].z, wv2.z, d2); d3 = fmaf(x0[c].z, wv3.z, d3);
        d0 = fmaf(x0[c].w, wv0.w, d0); d1 = fmaf(x0[c].w, wv1.w, d1);
        d2 = fmaf(x0[c].w, wv2.w, d2); d3 = fmaf(x0[c].w, wv3.w, d3);
    }

    // 64-lane butterfly, 4-way ILP
#pragma unroll
    for (int off = 32; off > 0; off >>= 1) {
        d0 += __shfl_xor(d0, off, 64);
        d1 += __shfl_xor(d1, off, 64);
        d2 += __shfl_xor(d2, off, 64);
        d3 += __shfl_xor(d3, off, 64);
    }

    const float g1 = ws[D + 1], g2 = ws[D + 2], g3 = ws[D + 3];

    // scalar recurrence: c_{i+1} = c_i + (c_i * d_i + g_i)
    float c1 = 1.f + d0;                    // s0 = d0, g0 = 0
    float c2 = c1 + fmaf(c1, d1, g1);
    float c3 = c2 + fmaf(c2, d2, g2);
    float c4 = c3 + fmaf(c3, d3, g3);

    float4* orow = (float4*)(out + (size_t)wave * D);
#pragma unroll
    for (int c = 0; c < CHUNKS; ++c) {
        const int idx = c * 64 + lane;
        float4 bs = bs4[idx];
        float4 o;
        o.x = fmaf(c4, x0[c].x, bs.x);
        o.y = fmaf(c4, x0[c].y, bs.y);
        o.z = fmaf(c4, x0[c].z, bs.z);
        o.w = fmaf(c4, x0[c].w, bs.w);
        orow[idx] = o;
    }
}

extern "C" void kernel_launch(void* const* d_in, const int* in_sizes, int n_in,
                              void* d_out, int out_size, void* d_ws, size_t ws_size,
                              hipStream_t stream) {
    const float* x = (const float*)d_in[0];
    const float* w = (const float*)d_in[1];
    const float* b = (const float*)d_in[2];
    float* out = (float*)d_out;
    float* ws  = (float*)d_ws;

    const int batch = in_sizes[0] / D;      // 16384

    precompute_kernel<<<1, 256, 0, stream>>>(w, b, ws);

    const int waves_per_block = 256 / 64;   // 4 rows per block
    const int grid = (batch + waves_per_block - 1) / waves_per_block;
    cross_main_kernel<<<grid, 256, 0, stream>>>(x, w, (const float*)ws, out, batch);
}

// Round 3
// 119.615 us; speedup vs baseline: 1.0529x; 1.0391x over previous
//
#include <hip/hip_runtime.h>

// DCN cross network, algebraically collapsed:
//   x_i = c_i * x0 + B_i,  B_i = sum_{j<i} b_j   (row-independent)
//   c_{i+1} = c_i + (c_i * d_i + g_i),  d_i = dot(x0, w_i),  g_i = dot(B_i, w_i)
//   out = c_4 * x0 + Bsum
// R3: 4 rows per wave — 16 outstanding x-loads, 16 independent dot chains,
// 16 interleaved butterfly chains, amortized w/Bsum loads. Attacks the
// latency-bound profile (VALUBusy 11%, HBM 30%) with per-wave MLP/ILP.

#define D 1024
#define LAYERS 4
#define CHUNKS 4
#define ROWS 4

__device__ inline float dot4(float4 a, float4 b) {
    return fmaf(a.x, b.x, fmaf(a.y, b.y, fmaf(a.z, b.z, a.w * b.w)));
}

// ws layout (floats): [0..1023] = Bsum, [1024..1027] = g0..g3 (g0 = 0)
__global__ __launch_bounds__(256) void precompute_kernel(
    const float* __restrict__ w,
    const float* __restrict__ b,
    float* __restrict__ ws)
{
    const int t = threadIdx.x;               // 0..255, each owns 4 floats
    const float4* b4 = (const float4*)b;
    const float4* w4 = (const float4*)w;

    float4 b0 = b4[t], b1 = b4[256 + t], b2 = b4[512 + t], b3 = b4[768 + t];
    float4 w1 = w4[256 + t], w2 = w4[512 + t], w3 = w4[768 + t];

    float4 s01, s012, bs;
    s01.x = b0.x + b1.x;  s01.y = b0.y + b1.y;
    s01.z = b0.z + b1.z;  s01.w = b0.w + b1.w;
    s012.x = s01.x + b2.x; s012.y = s01.y + b2.y;
    s012.z = s01.z + b2.z; s012.w = s01.w + b2.w;
    bs.x = s012.x + b3.x; bs.y = s012.y + b3.y;
    bs.z = s012.z + b3.z; bs.w = s012.w + b3.w;
    ((float4*)ws)[t] = bs;

    float g1 = dot4(b0, w1);
    float g2 = dot4(s01, w2);
    float g3 = dot4(s012, w3);

#pragma unroll
    for (int off = 32; off > 0; off >>= 1) {
        g1 += __shfl_xor(g1, off, 64);
        g2 += __shfl_xor(g2, off, 64);
        g3 += __shfl_xor(g3, off, 64);
    }

    __shared__ float red[3][4];
    const int wid = t >> 6, lane = t & 63;
    if (lane == 0) { red[0][wid] = g1; red[1][wid] = g2; red[2][wid] = g3; }
    __syncthreads();
    if (t == 0) {
        ws[D + 0] = 0.f;
        ws[D + 1] = red[0][0] + red[0][1] + red[0][2] + red[0][3];
        ws[D + 2] = red[1][0] + red[1][1] + red[1][2] + red[1][3];
        ws[D + 3] = red[2][0] + red[2][1] + red[2][2] + red[2][3];
    }
}

__global__ __launch_bounds__(256) void cross_main_kernel(
    const float* __restrict__ x,
    const float* __restrict__ w,
    const float* __restrict__ ws,
    float* __restrict__ out,
    int batch)
{
    const int wid  = (int)((blockIdx.x * blockDim.x + threadIdx.x) >> 6);
    const int lane = (int)(threadIdx.x & 63);
    const int row0 = wid * ROWS;
    if (row0 >= batch) return;

    const float4* w4  = (const float4*)w;
    const float4* bs4 = (const float4*)ws;

    // Issue all 16 x-loads up front — max memory-level parallelism.
    float4 x0[ROWS][CHUNKS];
#pragma unroll
    for (int r = 0; r < ROWS; ++r) {
        const float4* row = (const float4*)(x + (size_t)(row0 + r) * D);
#pragma unroll
        for (int c = 0; c < CHUNKS; ++c)
            x0[r][c] = row[c * 64 + lane];
    }

    float d[ROWS][LAYERS];
#pragma unroll
    for (int r = 0; r < ROWS; ++r)
#pragma unroll
        for (int l = 0; l < LAYERS; ++l) d[r][l] = 0.f;

#pragma unroll
    for (int c = 0; c < CHUNKS; ++c) {
        const int idx = c * 64 + lane;
        float4 wv[LAYERS];
        wv[0] = w4[idx];
        wv[1] = w4[256 + idx];
        wv[2] = w4[512 + idx];
        wv[3] = w4[768 + idx];
#pragma unroll
        for (int r = 0; r < ROWS; ++r) {
#pragma unroll
            for (int l = 0; l < LAYERS; ++l) {
                d[r][l] = fmaf(x0[r][c].x, wv[l].x, d[r][l]);
                d[r][l] = fmaf(x0[r][c].y, wv[l].y, d[r][l]);
                d[r][l] = fmaf(x0[r][c].z, wv[l].z, d[r][l]);
                d[r][l] = fmaf(x0[r][c].w, wv[l].w, d[r][l]);
            }
        }
    }

    // 16 interleaved butterfly chains — issue-bound, not latency-bound.
#pragma unroll
    for (int off = 32; off > 0; off >>= 1) {
#pragma unroll
        for (int r = 0; r < ROWS; ++r)
#pragma unroll
            for (int l = 0; l < LAYERS; ++l)
                d[r][l] += __shfl_xor(d[r][l], off, 64);
    }

    const float g1 = ws[D + 1], g2 = ws[D + 2], g3 = ws[D + 3];

    float c4v[ROWS];
#pragma unroll
    for (int r = 0; r < ROWS; ++r) {
        float c1 = 1.f + d[r][0];
        float c2 = c1 + fmaf(c1, d[r][1], g1);
        float c3 = c2 + fmaf(c2, d[r][2], g2);
        c4v[r]   = c3 + fmaf(c3, d[r][3], g3);
    }

#pragma unroll
    for (int c = 0; c < CHUNKS; ++c) {
        const int idx = c * 64 + lane;
        float4 bs = bs4[idx];
#pragma unroll
        for (int r = 0; r < ROWS; ++r) {
            float4 o;
            o.x = fmaf(c4v[r], x0[r][c].x, bs.x);
            o.y = fmaf(c4v[r], x0[r][c].y, bs.y);
            o.z = fmaf(c4v[r], x0[r][c].z, bs.z);
            o.w = fmaf(c4v[r], x0[r][c].w, bs.w);
            ((float4*)(out + (size_t)(row0 + r) * D))[idx] = o;
        }
    }
}

extern "C" void kernel_launch(void* const* d_in, const int* in_sizes, int n_in,
                              void* d_out, int out_size, void* d_ws, size_t ws_size,
                              hipStream_t stream) {
    const float* x = (const float*)d_in[0];
    const float* w = (const float*)d_in[1];
    const float* b = (const float*)d_in[2];
    float* out = (float*)d_out;
    float* ws  = (float*)d_ws;

    const int batch = in_sizes[0] / D;      // 16384

    precompute_kernel<<<1, 256, 0, stream>>>(w, b, ws);

    const int rows_per_block = ROWS * (256 / 64);   // 16 rows per block
    const int grid = (batch + rows_per_block - 1) / rows_per_block;  // 1024
    cross_main_kernel<<<grid, 256, 0, stream>>>(x, w, (const float*)ws, out, batch);
}

// Round 4
// 119.532 us; speedup vs baseline: 1.0537x; 1.0007x over previous
//
#include <hip/hip_runtime.h>

// DCN cross network, algebraically collapsed, fully fused (single kernel):
//   x_i = c_i * x0 + B_i,  B_i = sum_{j<i} b_j   (row-independent)
//   c_{i+1} = c_i + (c_i * d_i + g_i),  d_i = dot(x0, w_i),  g_i = dot(B_i, w_i)
//   out = c_4 * x0 + Bsum
// Each wave handles 4 rows (16 outstanding x-loads) and computes the
// row-independent g1..g3 / Bsum inline from w,b (L1-resident 32 KB) —
// no prologue kernel, no ws round-trip, no serialization.

#define D 1024
#define LAYERS 4
#define CHUNKS 4
#define ROWS 4

__global__ __launch_bounds__(256) void cross_fused_kernel(
    const float* __restrict__ x,
    const float* __restrict__ w,   // [4, 1024]
    const float* __restrict__ b,   // [4, 1024]
    float* __restrict__ out,
    int batch)
{
    const int wid  = (int)((blockIdx.x * blockDim.x + threadIdx.x) >> 6);
    const int lane = (int)(threadIdx.x & 63);
    const int row0 = wid * ROWS;
    if (row0 >= batch) return;

    const float4* w4 = (const float4*)w;
    const float4* b4 = (const float4*)b;

    // Issue all 16 x-loads up front — max memory-level parallelism.
    float4 x0[ROWS][CHUNKS];
#pragma unroll
    for (int r = 0; r < ROWS; ++r) {
        const float4* row = (const float4*)(x + (size_t)(row0 + r) * D);
#pragma unroll
        for (int c = 0; c < CHUNKS; ++c)
            x0[r][c] = row[c * 64 + lane];
    }

    float d[ROWS][LAYERS];
#pragma unroll
    for (int r = 0; r < ROWS; ++r)
#pragma unroll
        for (int l = 0; l < LAYERS; ++l) d[r][l] = 0.f;

    float g1 = 0.f, g2 = 0.f, g3 = 0.f;
    float4 Bsum[CHUNKS];

#pragma unroll
    for (int c = 0; c < CHUNKS; ++c) {
        const int idx = c * 64 + lane;
        float4 wv[LAYERS];
        wv[0] = w4[idx];
        wv[1] = w4[256 + idx];
        wv[2] = w4[512 + idx];
        wv[3] = w4[768 + idx];

        float4 bb0 = b4[idx];
        float4 bb1 = b4[256 + idx];
        float4 bb2 = b4[512 + idx];
        float4 bb3 = b4[768 + idx];

        // prefix bias sums: B1 = b0, B2 = b0+b1, B3 = b0+b1+b2
        float4 B2, B3, Bs;
        B2.x = bb0.x + bb1.x; B2.y = bb0.y + bb1.y;
        B2.z = bb0.z + bb1.z; B2.w = bb0.w + bb1.w;
        B3.x = B2.x + bb2.x;  B3.y = B2.y + bb2.y;
        B3.z = B2.z + bb2.z;  B3.w = B2.w + bb2.w;
        Bs.x = B3.x + bb3.x;  Bs.y = B3.y + bb3.y;
        Bs.z = B3.z + bb3.z;  Bs.w = B3.w + bb3.w;
        Bsum[c] = Bs;

        // g-dots (row-independent)
        g1 = fmaf(bb0.x, wv[1].x, g1); g1 = fmaf(bb0.y, wv[1].y, g1);
        g1 = fmaf(bb0.z, wv[1].z, g1); g1 = fmaf(bb0.w, wv[1].w, g1);
        g2 = fmaf(B2.x,  wv[2].x, g2); g2 = fmaf(B2.y,  wv[2].y, g2);
        g2 = fmaf(B2.z,  wv[2].z, g2); g2 = fmaf(B2.w,  wv[2].w, g2);
        g3 = fmaf(B3.x,  wv[3].x, g3); g3 = fmaf(B3.y,  wv[3].y, g3);
        g3 = fmaf(B3.z,  wv[3].z, g3); g3 = fmaf(B3.w,  wv[3].w, g3);

        // 16 independent d-dot chains
#pragma unroll
        for (int r = 0; r < ROWS; ++r) {
#pragma unroll
            for (int l = 0; l < LAYERS; ++l) {
                d[r][l] = fmaf(x0[r][c].x, wv[l].x, d[r][l]);
                d[r][l] = fmaf(x0[r][c].y, wv[l].y, d[r][l]);
                d[r][l] = fmaf(x0[r][c].z, wv[l].z, d[r][l]);
                d[r][l] = fmaf(x0[r][c].w, wv[l].w, d[r][l]);
            }
        }
    }

    // 19 interleaved butterfly chains — issue-bound, not latency-bound.
#pragma unroll
    for (int off = 32; off > 0; off >>= 1) {
#pragma unroll
        for (int r = 0; r < ROWS; ++r)
#pragma unroll
            for (int l = 0; l < LAYERS; ++l)
                d[r][l] += __shfl_xor(d[r][l], off, 64);
        g1 += __shfl_xor(g1, off, 64);
        g2 += __shfl_xor(g2, off, 64);
        g3 += __shfl_xor(g3, off, 64);
    }

    float c4v[ROWS];
#pragma unroll
    for (int r = 0; r < ROWS; ++r) {
        float c1 = 1.f + d[r][0];
        float c2 = c1 + fmaf(c1, d[r][1], g1);
        float c3 = c2 + fmaf(c2, d[r][2], g2);
        c4v[r]   = c3 + fmaf(c3, d[r][3], g3);
    }

#pragma unroll
    for (int c = 0; c < CHUNKS; ++c) {
        const int idx = c * 64 + lane;
#pragma unroll
        for (int r = 0; r < ROWS; ++r) {
            float4 o;
            o.x = fmaf(c4v[r], x0[r][c].x, Bsum[c].x);
            o.y = fmaf(c4v[r], x0[r][c].y, Bsum[c].y);
            o.z = fmaf(c4v[r], x0[r][c].z, Bsum[c].z);
            o.w = fmaf(c4v[r], x0[r][c].w, Bsum[c].w);
            ((float4*)(out + (size_t)(row0 + r) * D))[idx] = o;
        }
    }
}

extern "C" void kernel_launch(void* const* d_in, const int* in_sizes, int n_in,
                              void* d_out, int out_size, void* d_ws, size_t ws_size,
                              hipStream_t stream) {
    const float* x = (const float*)d_in[0];
    const float* w = (const float*)d_in[1];
    const float* b = (const float*)d_in[2];
    float* out = (float*)d_out;

    const int batch = in_sizes[0] / D;      // 16384

    const int rows_per_block = ROWS * (256 / 64);   // 16 rows per block
    const int grid = (batch + rows_per_block - 1) / rows_per_block;  // 1024
    cross_fused_kernel<<<grid, 256, 0, stream>>>(x, w, b, out, batch);
}

// Round 6
// 119.400 us; speedup vs baseline: 1.0548x; 1.0011x over previous
//
#include <hip/hip_runtime.h>

// DCN cross network, algebraically collapsed + software-pipelined:
//   x_i = c_i * x0 + B_i,  B_i = prefix-sum of biases (row-independent)
//   c_{i+1} = c_i + (c_i * d_i + g_i),  d_i = dot(x0, w_i),  g_i = dot(B_i, w_i)
//   out = c_4 * x0 + Bsum
// Each wave owns 4 consecutive rows, processed in a non-unrolled pipeline
// loop — row i+1's x-loads issue before row i's dot/butterfly/store, keeping
// the memory pipe continuously fed. Stores are nontemporal (out never
// re-read) to keep x L3-resident.

#define D 1024
#define CHUNKS 4
#define ITER 4

typedef float nfloat4 __attribute__((ext_vector_type(4)));  // native vec for NT store

__global__ __launch_bounds__(256) void cross_pipe_kernel(
    const float* __restrict__ x,
    const float* __restrict__ w,   // [4, 1024]
    const float* __restrict__ b,   // [4, 1024]
    float* __restrict__ out,
    int batch)
{
    const int wid  = (int)((blockIdx.x * blockDim.x + threadIdx.x) >> 6);
    const int lane = (int)(threadIdx.x & 63);
    const int row0 = wid * ITER;
    if (row0 >= batch) return;

    const float4* w4 = (const float4*)w;
    const float4* b4 = (const float4*)b;

    // ---- once per wave: Bsum (kept in regs) and g1..g3 ----
    float g1 = 0.f, g2 = 0.f, g3 = 0.f;
    float4 Bsum[CHUNKS];
#pragma unroll
    for (int c = 0; c < CHUNKS; ++c) {
        const int idx = c * 64 + lane;
        float4 bb0 = b4[idx], bb1 = b4[256 + idx];
        float4 bb2 = b4[512 + idx], bb3 = b4[768 + idx];
        float4 wv1 = w4[256 + idx], wv2 = w4[512 + idx], wv3 = w4[768 + idx];

        float4 B2, B3, Bs;
        B2.x = bb0.x + bb1.x; B2.y = bb0.y + bb1.y;
        B2.z = bb0.z + bb1.z; B2.w = bb0.w + bb1.w;
        B3.x = B2.x + bb2.x;  B3.y = B2.y + bb2.y;
        B3.z = B2.z + bb2.z;  B3.w = B2.w + bb2.w;
        Bs.x = B3.x + bb3.x;  Bs.y = B3.y + bb3.y;
        Bs.z = B3.z + bb3.z;  Bs.w = B3.w + bb3.w;
        Bsum[c] = Bs;

        g1 = fmaf(bb0.x, wv1.x, g1); g1 = fmaf(bb0.y, wv1.y, g1);
        g1 = fmaf(bb0.z, wv1.z, g1); g1 = fmaf(bb0.w, wv1.w, g1);
        g2 = fmaf(B2.x,  wv2.x, g2); g2 = fmaf(B2.y,  wv2.y, g2);
        g2 = fmaf(B2.z,  wv2.z, g2); g2 = fmaf(B2.w,  wv2.w, g2);
        g3 = fmaf(B3.x,  wv3.x, g3); g3 = fmaf(B3.y,  wv3.y, g3);
        g3 = fmaf(B3.z,  wv3.z, g3); g3 = fmaf(B3.w,  wv3.w, g3);
    }
#pragma unroll
    for (int off = 32; off > 0; off >>= 1) {
        g1 += __shfl_xor(g1, off, 64);
        g2 += __shfl_xor(g2, off, 64);
        g3 += __shfl_xor(g3, off, 64);
    }

    // ---- pipelined row loop: prefetch row i+1 while computing row i ----
    float4 xc[CHUNKS], xn[CHUNKS];
    {
        const float4* row = (const float4*)(x + (size_t)row0 * D);
#pragma unroll
        for (int c = 0; c < CHUNKS; ++c) xc[c] = row[c * 64 + lane];
    }

#pragma unroll 1   // keep the pipeline structure — do NOT flatten
    for (int i = 0; i < ITER; ++i) {
        const int rowi = row0 + i;
        // prefetch next row (clamped; last-iter prefetch is harmless reload)
        const int nrow = (rowi + 1 < batch) ? (rowi + 1) : rowi;
        const float4* nrp = (const float4*)(x + (size_t)nrow * D);
#pragma unroll
        for (int c = 0; c < CHUNKS; ++c) xn[c] = nrp[c * 64 + lane];

        // 4 independent layer-dot chains over this row
        float d0 = 0.f, d1 = 0.f, d2 = 0.f, d3 = 0.f;
#pragma unroll
        for (int c = 0; c < CHUNKS; ++c) {
            const int idx = c * 64 + lane;
            float4 wv0 = w4[idx];
            float4 wv1 = w4[256 + idx];
            float4 wv2 = w4[512 + idx];
            float4 wv3 = w4[768 + idx];
            d0 = fmaf(xc[c].x, wv0.x, d0); d1 = fmaf(xc[c].x, wv1.x, d1);
            d2 = fmaf(xc[c].x, wv2.x, d2); d3 = fmaf(xc[c].x, wv3.x, d3);
            d0 = fmaf(xc[c].y, wv0.y, d0); d1 = fmaf(xc[c].y, wv1.y, d1);
            d2 = fmaf(xc[c].y, wv2.y, d2); d3 = fmaf(xc[c].y, wv3.y, d3);
            d0 = fmaf(xc[c].z, wv0.z, d0); d1 = fmaf(xc[c].z, wv1.z, d1);
            d2 = fmaf(xc[c].z, wv2.z, d2); d3 = fmaf(xc[c].z, wv3.z, d3);
            d0 = fmaf(xc[c].w, wv0.w, d0); d1 = fmaf(xc[c].w, wv1.w, d1);
            d2 = fmaf(xc[c].w, wv2.w, d2); d3 = fmaf(xc[c].w, wv3.w, d3);
        }

#pragma unroll
        for (int off = 32; off > 0; off >>= 1) {
            d0 += __shfl_xor(d0, off, 64);
            d1 += __shfl_xor(d1, off, 64);
            d2 += __shfl_xor(d2, off, 64);
            d3 += __shfl_xor(d3, off, 64);
        }

        float c1 = 1.f + d0;
        float c2 = c1 + fmaf(c1, d1, g1);
        float c3 = c2 + fmaf(c2, d2, g2);
        float c4 = c3 + fmaf(c3, d3, g3);

        nfloat4* orow = (nfloat4*)(out + (size_t)rowi * D);
#pragma unroll
        for (int c = 0; c < CHUNKS; ++c) {
            const int idx = c * 64 + lane;
            nfloat4 o;
            o.x = fmaf(c4, xc[c].x, Bsum[c].x);
            o.y = fmaf(c4, xc[c].y, Bsum[c].y);
            o.z = fmaf(c4, xc[c].z, Bsum[c].z);
            o.w = fmaf(c4, xc[c].w, Bsum[c].w);
            __builtin_nontemporal_store(o, &orow[idx]);
        }

        // rotate pipeline registers
#pragma unroll
        for (int c = 0; c < CHUNKS; ++c) xc[c] = xn[c];
    }
}

extern "C" void kernel_launch(void* const* d_in, const int* in_sizes, int n_in,
                              void* d_out, int out_size, void* d_ws, size_t ws_size,
                              hipStream_t stream) {
    const float* x = (const float*)d_in[0];
    const float* w = (const float*)d_in[1];
    const float* b = (const float*)d_in[2];
    float* out = (float*)d_out;

    const int batch = in_sizes[0] / D;              // 16384
    const int rows_per_block = ITER * (256 / 64);   // 16 rows per block
    const int grid = (batch + rows_per_block - 1) / rows_per_block;  // 1024
    cross_pipe_kernel<<<grid, 256, 0, stream>>>(x, w, b, out, batch);
}